// Round 9
// baseline (201.994 us; speedup 1.0000x reference)
//
#include <hip/hip_runtime.h>
#include <math.h>

#define BATCH 64
#define NOBJ 16
#define NPRIOR 8732
#define NC 91
#define IMG 300.0f
#define GPB 1092                   // 8-row groups per batch (last group = 4 rows)
#define NGROUP (GPB * BATCH)       // 69888
#define CE_GRID 6144               // one-wave blocks

// ---------------------------------------------------------------- k_match
__global__ __launch_bounds__(1024) void k_match(
    const float* __restrict__ loc_data,
    const float* __restrict__ gt_boxes,
    const int*   __restrict__ gt_labels,
    const float* __restrict__ priors,
    int*   __restrict__ conf_t,
    int*   __restrict__ num_pos_b,
    float* __restrict__ ll_b)
{
    __shared__ float s_ov[NPRIOR];
    __shared__ unsigned char s_idx[NPRIOR];
    __shared__ float bx0[NOBJ], by0[NOBJ], bx1[NOBJ], by1[NOBJ], barea[NOBJ];
    __shared__ int   blab[NOBJ];
    __shared__ float rv[NOBJ][16];
    __shared__ int   ri[NOBJ][16];
    __shared__ int   bpi[NOBJ];
    __shared__ float red_f[16];
    __shared__ int   red_i[16];

    const int b    = blockIdx.x;
    const int tid  = threadIdx.x;
    const int lane = tid & 63;
    const int wave = tid >> 6;

    if (tid < NOBJ) {
        float4 g = ((const float4*)gt_boxes)[(size_t)b * NOBJ + tid];
        float x0 = g.x * (1.0f / IMG), y0 = g.y * (1.0f / IMG);
        float x1 = g.z * (1.0f / IMG), y1 = g.w * (1.0f / IMG);
        bx0[tid] = x0; by0[tid] = y0; bx1[tid] = x1; by1[tid] = y1;
        barea[tid] = (x1 - x0) * (y1 - y0);
        blab[tid] = gt_labels[b * NOBJ + tid];
    }
    __syncthreads();

    float bv[NOBJ];
    int   bi[NOBJ];
#pragma unroll
    for (int j = 0; j < NOBJ; j++) { bv[j] = -1.0f; bi[j] = 0x7fffffff; }

    for (int p = tid; p < NPRIOR; p += 1024) {
        float4 pr = ((const float4*)priors)[p];
        float cx = pr.x, cy = pr.y, w = pr.z, h = pr.w;
        float px0 = cx - 0.5f * w, py0 = cy - 0.5f * h;
        float px1 = cx + 0.5f * w, py1 = cy + 0.5f * h;
        float pa = w * h;
        float maxv = -1.0f; int maxj = 0;
#pragma unroll
        for (int j = 0; j < NOBJ; j++) {
            float ltx = fmaxf(bx0[j], px0), lty = fmaxf(by0[j], py0);
            float rbx = fminf(bx1[j], px1), rby = fminf(by1[j], py1);
            float iw = fmaxf(rbx - ltx, 0.0f), ih = fmaxf(rby - lty, 0.0f);
            float inter = iw * ih;
            float iou = inter / (barea[j] + pa - inter);
            if (iou > maxv) { maxv = iou; maxj = j; }
            if (iou > bv[j]) { bv[j] = iou; bi[j] = p; }
        }
        s_ov[p]  = maxv;
        s_idx[p] = (unsigned char)maxj;
    }

#pragma unroll
    for (int j = 0; j < NOBJ; j++) {
        float v = bv[j]; int ix = bi[j];
        for (int off = 32; off; off >>= 1) {
            float v2 = __shfl_xor(v, off);
            int   i2 = __shfl_xor(ix, off);
            if (v2 > v || (v2 == v && i2 < ix)) { v = v2; ix = i2; }
        }
        if (lane == 0) { rv[j][wave] = v; ri[j][wave] = ix; }
    }
    __syncthreads();
    if (tid < NOBJ) {
        int j = tid;
        float v = rv[j][0]; int ix = ri[j][0];
        for (int w2 = 1; w2 < 16; w2++) {
            float v2 = rv[j][w2]; int i2 = ri[j][w2];
            if (v2 > v || (v2 == v && i2 < ix)) { v = v2; ix = i2; }
        }
        bpi[j] = ix;
    }
    __syncthreads();
    if (tid == 0) {
        for (int j = 0; j < NOBJ; j++) s_ov[bpi[j]] = 2.0f;
        for (int j = 0; j < NOBJ; j++) s_idx[bpi[j]] = (unsigned char)j;
    }
    __syncthreads();

    int np_local = 0;
    float ll_local = 0.0f;
    for (int p = tid; p < NPRIOR; p += 1024) {
        float ov = s_ov[p];
        int ti = (int)s_idx[p];
        int conf = (ov < 0.5f) ? 0 : blab[ti];
        conf_t[(size_t)b * NPRIOR + p] = conf;
        if (conf > 0) {
            np_local++;
            float4 pr = ((const float4*)priors)[p];
            float cx = pr.x, cy = pr.y, w = pr.z, h = pr.w;
            float mx0 = bx0[ti], my0 = by0[ti], mx1 = bx1[ti], my1 = by1[ti];
            float g0 = ((mx0 + mx1) * 0.5f - cx) / (0.1f * w);
            float g1 = ((my0 + my1) * 0.5f - cy) / (0.1f * h);
            float g2 = logf((mx1 - mx0) / w) * 5.0f;
            float g3 = logf((my1 - my0) / h) * 5.0f;
            float4 lv = ((const float4*)loc_data)[(size_t)b * NPRIOR + p];
            float d0 = lv.x - g0, d1 = lv.y - g1, d2 = lv.z - g2, d3 = lv.w - g3;
            float a0 = fabsf(d0), a1 = fabsf(d1), a2 = fabsf(d2), a3 = fabsf(d3);
            ll_local += (a0 < 1.f ? 0.5f * d0 * d0 : a0 - 0.5f)
                      + (a1 < 1.f ? 0.5f * d1 * d1 : a1 - 0.5f)
                      + (a2 < 1.f ? 0.5f * d2 * d2 : a2 - 0.5f)
                      + (a3 < 1.f ? 0.5f * d3 * d3 : a3 - 0.5f);
        }
    }
    for (int off = 32; off; off >>= 1) {
        ll_local += __shfl_xor(ll_local, off);
        np_local += __shfl_xor(np_local, off);
    }
    if (lane == 0) { red_f[wave] = ll_local; red_i[wave] = np_local; }
    __syncthreads();
    if (tid == 0) {
        float ll = 0.0f; int np = 0;
        for (int w2 = 0; w2 < 16; w2++) { ll += red_f[w2]; np += red_i[w2]; }
        num_pos_b[b] = np;
        ll_b[b] = ll;
    }
}

// ---------------------------------------------------------------- k_ce
// One-wave persistent blocks, zero barriers, depth-2 register pipeline,
// conf_t prefetched one phase ahead. Overwrite-idempotent (duplication-safe).

#define CE_ISSUE(gg, R0, R1, R2, NF)                                           \
    {   int b_ = (gg) / GPB, ci_ = (gg) - b_ * GPB;                            \
        int p0_ = ci_ * 8;                                                     \
        int rows_ = min(8, NPRIOR - p0_);                                      \
        NF = (rows_ * NC) >> 2;                                                \
        const float4* s_ = (const float4*)(conf_data + ((size_t)b_ * NPRIOR + p0_) * NC); \
        R0 = s_[tid];                                                          \
        if (tid + 64  < NF) R1 = s_[tid + 64];                                 \
        if (tid + 128 < NF) R2 = s_[tid + 128]; }

#define CT_LOAD(gg)                                                            \
    ( conf_t[(size_t)((gg) / GPB) * NPRIOR + ((gg) - ((gg) / GPB) * GPB) * 8 + (tid >> 3)] )

#define CE_WRITE(BUF, R0, R1, R2, NF)                                          \
    {   float4* d_ = (float4*)sbuf[BUF];                                       \
        d_[tid] = R0;                                                          \
        if (tid + 64  < NF) d_[tid + 64]  = R1;                                \
        if (tid + 128 < NF) d_[tid + 128] = R2; }

#define CE_COMPUTE(gg, BUF, TG)                                                \
    {   int b_ = (gg) / GPB, ci_ = (gg) - b_ * GPB;                            \
        int p0_ = ci_ * 8;                                                     \
        int rows_ = min(8, NPRIOR - p0_);                                      \
        int rr_ = tid >> 3, q_ = tid & 7;                                      \
        if (rr_ < rows_) {                                                     \
            const float* row_ = sbuf[BUF] + rr_ * NC;                          \
            float s_ = 0.0f;                                                   \
            _Pragma("unroll")                                                  \
            for (int i_ = q_; i_ < NC; i_ += 8) s_ += __expf(row_[i_]);        \
            s_ += __shfl_xor(s_, 1);                                           \
            s_ += __shfl_xor(s_, 2);                                           \
            s_ += __shfl_xor(s_, 4);                                           \
            if (q_ == 0) {                                                     \
                size_t o_ = (size_t)b_ * NPRIOR + p0_ + rr_;                   \
                int tgt_ = TG;                                                 \
                float ce_ = __logf(s_) - row_[tgt_];                           \
                if (tgt_ > 0) { pos_acc += ce_; mine[o_] = 0.0f; }             \
                else          { mine[o_] = fmaxf(ce_, 0.0f); }                 \
            } } }

__global__ __launch_bounds__(64) void k_ce(
    const float* __restrict__ conf_data,
    const int*   __restrict__ conf_t,
    float* __restrict__ mine,
    float* __restrict__ lc_part)
{
    __shared__ float sbuf[2][8 * NC];
    const int tid = threadIdx.x;
    const int G = CE_GRID;

    float4 a0, a1, a2, b0, b1, b2;
    int nfA = 0, nfB = 0;
    float pos_acc = 0.0f;

    int g = blockIdx.x;
    CE_ISSUE(g, a0, a1, a2, nfA);
    int tcur = CT_LOAD(g);
    if (g + G < NGROUP) CE_ISSUE(g + G, b0, b1, b2, nfB);
    CE_WRITE(0, a0, a1, a2, nfA);

    for (; g < NGROUP; g += 2 * G) {
        int tnext = (g + G < NGROUP) ? CT_LOAD(g + G) : 0;
        if (g + 2 * G < NGROUP) CE_ISSUE(g + 2 * G, a0, a1, a2, nfA);
        CE_COMPUTE(g, 0, tcur);
        if (g + G < NGROUP) {
            CE_WRITE(1, b0, b1, b2, nfB);
            int tn2 = (g + 2 * G < NGROUP) ? CT_LOAD(g + 2 * G) : 0;
            if (g + 3 * G < NGROUP) CE_ISSUE(g + 3 * G, b0, b1, b2, nfB);
            CE_COMPUTE(g + G, 1, tnext);
            if (g + 2 * G < NGROUP) CE_WRITE(0, a0, a1, a2, nfA);
            tcur = tn2;
        }
    }

    for (int off = 32; off; off >>= 1) pos_acc += __shfl_xor(pos_acc, off);
    if (tid == 0) lc_part[blockIdx.x] = pos_acc;
}

// ---------------------------------------------------------------- k_select
__global__ __launch_bounds__(1024) void k_select(
    const float* __restrict__ mine,
    const int*   __restrict__ num_pos_b,
    float* __restrict__ lc2)
{
    __shared__ float vals[NPRIOR];
    __shared__ int   hist[8][256];
    __shared__ int   wtot[4];
    __shared__ unsigned s_prefix;
    __shared__ int   s_remk;
    __shared__ float red_f[16];
    __shared__ int   red_i[16];

    const int b = blockIdx.x;
    const int tid = threadIdx.x;
    const int lane = tid & 63;
    const int wave = tid >> 6;
    const int rep = wave & 7;

    for (int i = tid; i < NPRIOR; i += 1024)
        vals[i] = mine[(size_t)b * NPRIOR + i];

    int np = num_pos_b[b];
    const int kk = min(max(3 * np, 1), NPRIOR - 1);
    if (tid == 0) { s_prefix = 0u; s_remk = kk; }

#pragma unroll
    for (int pass = 0; pass < 4; pass++) {
        const int shift = 24 - pass * 8;
        __syncthreads();
        ((int*)hist)[tid] = 0;
        ((int*)hist)[tid + 1024] = 0;
        __syncthreads();
        const unsigned pfx = s_prefix;
        const int      rem = s_remk;
        const unsigned mask = (shift == 24) ? 0u : (~0u << (shift + 8));
        for (int i = tid; i < NPRIOR; i += 1024) {
            unsigned key = __float_as_uint(vals[i]);
            if ((key & mask) == pfx)
                atomicAdd(&hist[rep][(key >> shift) & 0xFF], 1);
        }
        __syncthreads();
        int h = 0, v = 0;
        if (tid < 256) {
            h = hist[0][tid] + hist[1][tid] + hist[2][tid] + hist[3][tid]
              + hist[4][tid] + hist[5][tid] + hist[6][tid] + hist[7][tid];
            v = h;
#pragma unroll
            for (int off = 1; off < 64; off <<= 1) {
                int t = __shfl_down(v, off);
                v += (lane + off < 64) ? t : 0;
            }
            if (lane == 0) wtot[wave] = v;
        }
        __syncthreads();
        if (tid < 256) {
            int hi = 0;
#pragma unroll
            for (int w2 = 0; w2 < 4; w2++) if (w2 > wave) hi += wtot[w2];
            int S = (v - h) + hi;
            if (S < rem && S + h >= rem) {
                s_prefix = pfx | ((unsigned)tid << shift);
                s_remk = rem - S;
            }
        }
    }
    __syncthreads();

    const float T = __uint_as_float(s_prefix);
    float sum_gt = 0.0f;
    int   cnt_gt = 0;
    for (int i = tid; i < NPRIOR; i += 1024) {
        float v = vals[i];
        if (v > T) { sum_gt += v; cnt_gt++; }
    }
    for (int off = 32; off; off >>= 1) {
        sum_gt += __shfl_xor(sum_gt, off);
        cnt_gt += __shfl_xor(cnt_gt, off);
    }
    if (lane == 0) { red_f[wave] = sum_gt; red_i[wave] = cnt_gt; }
    __syncthreads();
    if (tid == 0) {
        float s = 0.0f; int c = 0;
        for (int w2 = 0; w2 < 16; w2++) { s += red_f[w2]; c += red_i[w2]; }
        lc2[b] = s + (float)(kk - c) * T;
    }
}

// ---------------------------------------------------------------- k_final
__global__ __launch_bounds__(1024) void k_final(
    const float* __restrict__ lc_part, const float* __restrict__ lc2,
    const float* __restrict__ ll_b, const int* __restrict__ np_b,
    float* __restrict__ out)
{
    __shared__ float rf[16][2];
    __shared__ int   rn[16];
    const int tid = threadIdx.x;
    float lc = 0.0f;
    for (int i = tid; i < CE_GRID; i += 1024) lc += lc_part[i];
    float ll = 0.0f; int np = 0;
    if (tid < BATCH) { lc += lc2[tid]; ll = ll_b[tid]; np = np_b[tid]; }
    for (int off = 32; off; off >>= 1) {
        lc += __shfl_xor(lc, off);
        ll += __shfl_xor(ll, off);
        np += __shfl_xor(np, off);
    }
    const int lane = tid & 63, wave = tid >> 6;
    if (lane == 0) { rf[wave][0] = lc; rf[wave][1] = ll; rn[wave] = np; }
    __syncthreads();
    if (tid == 0) {
        float lcT = 0.0f, llT = 0.0f; int npT = 0;
        for (int w = 0; w < 16; w++) { lcT += rf[w][0]; llT += rf[w][1]; npT += rn[w]; }
        float N = fmaxf((float)npT, 1.0f);
        out[0] = llT / N;
        out[1] = lcT / N;
    }
}

// ---------------------------------------------------------------- launch
// ATTRIBUTION ROUND: k_ce launched 3x (overwrite-idempotent, deterministic).
// dur_us - 131 - ~2us(launches) = 2 * X(k_ce).
extern "C" void kernel_launch(void* const* d_in, const int* in_sizes, int n_in,
                              void* d_out, int out_size, void* d_ws, size_t ws_size,
                              hipStream_t stream)
{
    const float* loc_data  = (const float*)d_in[0];
    const float* conf_data = (const float*)d_in[1];
    const float* gt_boxes  = (const float*)d_in[2];
    const int*   gt_labels = (const int*)d_in[3];
    const float* priors    = (const float*)d_in[4];
    float* out = (float*)d_out;

    char* ws = (char*)d_ws;
    float* ll_b     = (float*)(ws + 0);
    int*   np_b     = (int*)(ws + 256);
    float* lc2      = (float*)(ws + 512);
    float* lc_part  = (float*)(ws + 1024);
    int*   conf_t   = (int*)(ws + 32768);
    float* mine     = (float*)(ws + 32768 + (size_t)BATCH * NPRIOR * 4);

    hipLaunchKernelGGL(k_match, dim3(BATCH), dim3(1024), 0, stream,
                       loc_data, gt_boxes, gt_labels, priors, conf_t, np_b, ll_b);
    hipLaunchKernelGGL(k_ce, dim3(CE_GRID), dim3(64), 0, stream,
                       conf_data, conf_t, mine, lc_part);
    hipLaunchKernelGGL(k_ce, dim3(CE_GRID), dim3(64), 0, stream,
                       conf_data, conf_t, mine, lc_part);
    hipLaunchKernelGGL(k_ce, dim3(CE_GRID), dim3(64), 0, stream,
                       conf_data, conf_t, mine, lc_part);
    hipLaunchKernelGGL(k_select, dim3(BATCH), dim3(1024), 0, stream,
                       mine, np_b, lc2);
    hipLaunchKernelGGL(k_final, dim3(1), dim3(1024), 0, stream,
                       lc_part, lc2, ll_b, np_b, out);
}

// Round 10
// 184.518 us; speedup vs baseline: 1.0947x; 1.0947x over previous
//
#include <hip/hip_runtime.h>
#include <math.h>

#define BATCH 64
#define NOBJ 16
#define NPRIOR 8732
#define NC 91
#define IMG 300.0f
#define GPB 1092                   // 8-row groups per batch (last group = 4 rows)
#define NGROUP (GPB * BATCH)       // 69888
#define CE_GRID 6144               // one-wave blocks
#define NREP 4
#define HPAD 257

// ---------------------------------------------------------------- k_match
__global__ __launch_bounds__(1024) void k_match(
    const float* __restrict__ loc_data,
    const float* __restrict__ gt_boxes,
    const int*   __restrict__ gt_labels,
    const float* __restrict__ priors,
    int*   __restrict__ conf_t,
    int*   __restrict__ num_pos_b,
    float* __restrict__ ll_b)
{
    __shared__ float s_ov[NPRIOR];
    __shared__ unsigned char s_idx[NPRIOR];
    __shared__ float bx0[NOBJ], by0[NOBJ], bx1[NOBJ], by1[NOBJ], barea[NOBJ];
    __shared__ int   blab[NOBJ];
    __shared__ float rv[NOBJ][16];
    __shared__ int   ri[NOBJ][16];
    __shared__ int   bpi[NOBJ];
    __shared__ float red_f[16];
    __shared__ int   red_i[16];

    const int b    = blockIdx.x;
    const int tid  = threadIdx.x;
    const int lane = tid & 63;
    const int wave = tid >> 6;

    if (tid < NOBJ) {
        float4 g = ((const float4*)gt_boxes)[(size_t)b * NOBJ + tid];
        float x0 = g.x * (1.0f / IMG), y0 = g.y * (1.0f / IMG);
        float x1 = g.z * (1.0f / IMG), y1 = g.w * (1.0f / IMG);
        bx0[tid] = x0; by0[tid] = y0; bx1[tid] = x1; by1[tid] = y1;
        barea[tid] = (x1 - x0) * (y1 - y0);
        blab[tid] = gt_labels[b * NOBJ + tid];
    }
    __syncthreads();

    float bv[NOBJ];
    int   bi[NOBJ];
#pragma unroll
    for (int j = 0; j < NOBJ; j++) { bv[j] = -1.0f; bi[j] = 0x7fffffff; }

    for (int p = tid; p < NPRIOR; p += 1024) {
        float4 pr = ((const float4*)priors)[p];
        float cx = pr.x, cy = pr.y, w = pr.z, h = pr.w;
        float px0 = cx - 0.5f * w, py0 = cy - 0.5f * h;
        float px1 = cx + 0.5f * w, py1 = cy + 0.5f * h;
        float pa = w * h;
        float maxv = -1.0f; int maxj = 0;
#pragma unroll
        for (int j = 0; j < NOBJ; j++) {
            float ltx = fmaxf(bx0[j], px0), lty = fmaxf(by0[j], py0);
            float rbx = fminf(bx1[j], px1), rby = fminf(by1[j], py1);
            float iw = fmaxf(rbx - ltx, 0.0f), ih = fmaxf(rby - lty, 0.0f);
            float inter = iw * ih;
            float iou = inter / (barea[j] + pa - inter);
            if (iou > maxv) { maxv = iou; maxj = j; }
            if (iou > bv[j]) { bv[j] = iou; bi[j] = p; }
        }
        s_ov[p]  = maxv;
        s_idx[p] = (unsigned char)maxj;
    }

#pragma unroll
    for (int j = 0; j < NOBJ; j++) {
        float v = bv[j]; int ix = bi[j];
        for (int off = 32; off; off >>= 1) {
            float v2 = __shfl_xor(v, off);
            int   i2 = __shfl_xor(ix, off);
            if (v2 > v || (v2 == v && i2 < ix)) { v = v2; ix = i2; }
        }
        if (lane == 0) { rv[j][wave] = v; ri[j][wave] = ix; }
    }
    __syncthreads();
    if (tid < NOBJ) {
        int j = tid;
        float v = rv[j][0]; int ix = ri[j][0];
        for (int w2 = 1; w2 < 16; w2++) {
            float v2 = rv[j][w2]; int i2 = ri[j][w2];
            if (v2 > v || (v2 == v && i2 < ix)) { v = v2; ix = i2; }
        }
        bpi[j] = ix;
    }
    __syncthreads();
    if (tid == 0) {
        for (int j = 0; j < NOBJ; j++) s_ov[bpi[j]] = 2.0f;
        for (int j = 0; j < NOBJ; j++) s_idx[bpi[j]] = (unsigned char)j;
    }
    __syncthreads();

    int np_local = 0;
    float ll_local = 0.0f;
    for (int p = tid; p < NPRIOR; p += 1024) {
        float ov = s_ov[p];
        int ti = (int)s_idx[p];
        int conf = (ov < 0.5f) ? 0 : blab[ti];
        conf_t[(size_t)b * NPRIOR + p] = conf;
        if (conf > 0) {
            np_local++;
            float4 pr = ((const float4*)priors)[p];
            float cx = pr.x, cy = pr.y, w = pr.z, h = pr.w;
            float mx0 = bx0[ti], my0 = by0[ti], mx1 = bx1[ti], my1 = by1[ti];
            float g0 = ((mx0 + mx1) * 0.5f - cx) / (0.1f * w);
            float g1 = ((my0 + my1) * 0.5f - cy) / (0.1f * h);
            float g2 = logf((mx1 - mx0) / w) * 5.0f;
            float g3 = logf((my1 - my0) / h) * 5.0f;
            float4 lv = ((const float4*)loc_data)[(size_t)b * NPRIOR + p];
            float d0 = lv.x - g0, d1 = lv.y - g1, d2 = lv.z - g2, d3 = lv.w - g3;
            float a0 = fabsf(d0), a1 = fabsf(d1), a2 = fabsf(d2), a3 = fabsf(d3);
            ll_local += (a0 < 1.f ? 0.5f * d0 * d0 : a0 - 0.5f)
                      + (a1 < 1.f ? 0.5f * d1 * d1 : a1 - 0.5f)
                      + (a2 < 1.f ? 0.5f * d2 * d2 : a2 - 0.5f)
                      + (a3 < 1.f ? 0.5f * d3 * d3 : a3 - 0.5f);
        }
    }
    for (int off = 32; off; off >>= 1) {
        ll_local += __shfl_xor(ll_local, off);
        np_local += __shfl_xor(np_local, off);
    }
    if (lane == 0) { red_f[wave] = ll_local; red_i[wave] = np_local; }
    __syncthreads();
    if (tid == 0) {
        float ll = 0.0f; int np = 0;
        for (int w2 = 0; w2 < 16; w2++) { ll += red_f[w2]; np += red_i[w2]; }
        num_pos_b[b] = np;
        ll_b[b] = ll;
    }
}

// ---------------------------------------------------------------- k_ce
// One-wave persistent blocks, zero barriers, depth-2 register pipeline.

#define CE_ISSUE(gg, R0, R1, R2, NF)                                           \
    {   int b_ = (gg) / GPB, ci_ = (gg) - b_ * GPB;                            \
        int p0_ = ci_ * 8;                                                     \
        int rows_ = min(8, NPRIOR - p0_);                                      \
        NF = (rows_ * NC) >> 2;                                                \
        const float4* s_ = (const float4*)(conf_data + ((size_t)b_ * NPRIOR + p0_) * NC); \
        R0 = s_[tid];                                                          \
        if (tid + 64  < NF) R1 = s_[tid + 64];                                 \
        if (tid + 128 < NF) R2 = s_[tid + 128]; }

#define CT_LOAD(gg)                                                            \
    ( conf_t[(size_t)((gg) / GPB) * NPRIOR + ((gg) - ((gg) / GPB) * GPB) * 8 + (tid >> 3)] )

#define CE_WRITE(BUF, R0, R1, R2, NF)                                          \
    {   float4* d_ = (float4*)sbuf[BUF];                                       \
        d_[tid] = R0;                                                          \
        if (tid + 64  < NF) d_[tid + 64]  = R1;                                \
        if (tid + 128 < NF) d_[tid + 128] = R2; }

#define CE_COMPUTE(gg, BUF, TG)                                                \
    {   int b_ = (gg) / GPB, ci_ = (gg) - b_ * GPB;                            \
        int p0_ = ci_ * 8;                                                     \
        int rows_ = min(8, NPRIOR - p0_);                                      \
        int rr_ = tid >> 3, q_ = tid & 7;                                      \
        if (rr_ < rows_) {                                                     \
            const float* row_ = sbuf[BUF] + rr_ * NC;                          \
            float s_ = 0.0f;                                                   \
            _Pragma("unroll")                                                  \
            for (int i_ = q_; i_ < NC; i_ += 8) s_ += __expf(row_[i_]);        \
            s_ += __shfl_xor(s_, 1);                                           \
            s_ += __shfl_xor(s_, 2);                                           \
            s_ += __shfl_xor(s_, 4);                                           \
            if (q_ == 0) {                                                     \
                size_t o_ = (size_t)b_ * NPRIOR + p0_ + rr_;                   \
                int tgt_ = TG;                                                 \
                float ce_ = __logf(s_) - row_[tgt_];                           \
                if (tgt_ > 0) { pos_acc += ce_; mine[o_] = 0.0f; }             \
                else          { mine[o_] = fmaxf(ce_, 0.0f); }                 \
            } } }

__global__ __launch_bounds__(64) void k_ce(
    const float* __restrict__ conf_data,
    const int*   __restrict__ conf_t,
    float* __restrict__ mine,
    float* __restrict__ lc_part)
{
    __shared__ float sbuf[2][8 * NC];
    const int tid = threadIdx.x;
    const int G = CE_GRID;

    float4 a0, a1, a2, b0, b1, b2;
    int nfA = 0, nfB = 0;
    float pos_acc = 0.0f;

    int g = blockIdx.x;
    CE_ISSUE(g, a0, a1, a2, nfA);
    int tcur = CT_LOAD(g);
    if (g + G < NGROUP) CE_ISSUE(g + G, b0, b1, b2, nfB);
    CE_WRITE(0, a0, a1, a2, nfA);

    for (; g < NGROUP; g += 2 * G) {
        int tnext = (g + G < NGROUP) ? CT_LOAD(g + G) : 0;
        if (g + 2 * G < NGROUP) CE_ISSUE(g + 2 * G, a0, a1, a2, nfA);
        CE_COMPUTE(g, 0, tcur);
        if (g + G < NGROUP) {
            CE_WRITE(1, b0, b1, b2, nfB);
            int tn2 = (g + 2 * G < NGROUP) ? CT_LOAD(g + 2 * G) : 0;
            if (g + 3 * G < NGROUP) CE_ISSUE(g + 3 * G, b0, b1, b2, nfB);
            CE_COMPUTE(g + G, 1, tnext);
            if (g + 2 * G < NGROUP) CE_WRITE(0, a0, a1, a2, nfA);
            tcur = tn2;
        }
    }

    for (int off = 32; off; off >>= 1) pos_acc += __shfl_xor(pos_acc, off);
    if (tid == 0) lc_part[blockIdx.x] = pos_acc;
}

// ---------------------------------------------------------------- k_select
// Exact top-k value-sum via 4-pass radix select. Histogram uses
// ballot-leader aggregation: one atomicAdd per distinct digit per wave
// (kills the same-address lane serialization of pass 0, where ~97% of keys
// share top byte 0x40). hist padded to [NREP][257] so replicas' same bin
// maps to different banks. Uniform trip-count loop (ballots need full wave).
__global__ __launch_bounds__(1024) void k_select(
    const float* __restrict__ mine,
    const int*   __restrict__ num_pos_b,
    float* __restrict__ lc2)
{
    __shared__ float vals[NPRIOR];        // 34928 B
    __shared__ int   hist[NREP][HPAD];    // 4112 B
    __shared__ int   wtot[4];
    __shared__ unsigned s_prefix;
    __shared__ int   s_remk;
    __shared__ float red_f[16];
    __shared__ int   red_i[16];

    const int b = blockIdx.x;
    const int tid = threadIdx.x;
    const int lane = tid & 63;
    const int wave = tid >> 6;
    const int rep = wave & (NREP - 1);

    const float4* m4 = (const float4*)(mine + (size_t)b * NPRIOR);  // 8732%4==0
    for (int i = tid; i < NPRIOR / 4; i += 1024)
        ((float4*)vals)[i] = m4[i];

    int np = num_pos_b[b];
    const int kk = min(max(3 * np, 1), NPRIOR - 1);
    if (tid == 0) { s_prefix = 0u; s_remk = kk; }

#pragma unroll
    for (int pass = 0; pass < 4; pass++) {
        const int shift = 24 - pass * 8;
        __syncthreads();                   // prev select write + prev reads done
        for (int i = tid; i < NREP * HPAD; i += 1024) ((int*)hist)[i] = 0;
        __syncthreads();
        const unsigned pfx = s_prefix;
        const int      rem = s_remk;
        const unsigned mask = (shift == 24) ? 0u : (~0u << (shift + 8));
#pragma unroll
        for (int k = 0; k < (NPRIOR + 1023) / 1024; k++) {   // uniform: 9 iters
            int i = tid + k * 1024;
            bool inb = (i < NPRIOR);
            unsigned key = inb ? __float_as_uint(vals[i]) : 0u;
            bool pred = inb && ((key & mask) == pfx);
            unsigned digit = (key >> shift) & 0xFF;
            unsigned long long act = __ballot(pred);
            unsigned long long peers = act;
#pragma unroll
            for (int bit = 0; bit < 8; bit++) {
                unsigned long long vote = __ballot(pred && ((digit >> bit) & 1));
                peers &= ((digit >> bit) & 1) ? vote : ~vote;
            }
            if (pred) {
                int leader = __ffsll((unsigned long long)peers) - 1;
                if (lane == leader)
                    atomicAdd(&hist[rep][digit], (int)__popcll(peers));
            }
        }
        __syncthreads();
        int h = 0, v = 0;
        if (tid < 256) {
            h = hist[0][tid] + hist[1][tid] + hist[2][tid] + hist[3][tid];
            v = h;                          // inclusive suffix sum within wave
#pragma unroll
            for (int off = 1; off < 64; off <<= 1) {
                int t = __shfl_down(v, off);
                v += (lane + off < 64) ? t : 0;
            }
            if (lane == 0) wtot[wave] = v;
        }
        __syncthreads();                   // full-block barrier
        if (tid < 256) {
            int hi = 0;
#pragma unroll
            for (int w2 = 0; w2 < 4; w2++) if (w2 > wave) hi += wtot[w2];
            int S = (v - h) + hi;          // keys strictly in higher bins
            if (S < rem && S + h >= rem) { // unique bin
                s_prefix = pfx | ((unsigned)tid << shift);
                s_remk = rem - S;
            }
        }
    }
    __syncthreads();

    const float T = __uint_as_float(s_prefix);
    float sum_gt = 0.0f;
    int   cnt_gt = 0;
    for (int i = tid; i < NPRIOR; i += 1024) {
        float v = vals[i];
        if (v > T) { sum_gt += v; cnt_gt++; }
    }
    for (int off = 32; off; off >>= 1) {
        sum_gt += __shfl_xor(sum_gt, off);
        cnt_gt += __shfl_xor(cnt_gt, off);
    }
    if (lane == 0) { red_f[wave] = sum_gt; red_i[wave] = cnt_gt; }
    __syncthreads();
    if (tid == 0) {
        float s = 0.0f; int c = 0;
        for (int w2 = 0; w2 < 16; w2++) { s += red_f[w2]; c += red_i[w2]; }
        lc2[b] = s + (float)(kk - c) * T;
    }
}

// ---------------------------------------------------------------- k_final
__global__ __launch_bounds__(1024) void k_final(
    const float* __restrict__ lc_part, const float* __restrict__ lc2,
    const float* __restrict__ ll_b, const int* __restrict__ np_b,
    float* __restrict__ out)
{
    __shared__ float rf[16][2];
    __shared__ int   rn[16];
    const int tid = threadIdx.x;
    float lc = 0.0f;
    for (int i = tid; i < CE_GRID; i += 1024) lc += lc_part[i];
    float ll = 0.0f; int np = 0;
    if (tid < BATCH) { lc += lc2[tid]; ll = ll_b[tid]; np = np_b[tid]; }
    for (int off = 32; off; off >>= 1) {
        lc += __shfl_xor(lc, off);
        ll += __shfl_xor(ll, off);
        np += __shfl_xor(np, off);
    }
    const int lane = tid & 63, wave = tid >> 6;
    if (lane == 0) { rf[wave][0] = lc; rf[wave][1] = ll; rn[wave] = np; }
    __syncthreads();
    if (tid == 0) {
        float lcT = 0.0f, llT = 0.0f; int npT = 0;
        for (int w = 0; w < 16; w++) { lcT += rf[w][0]; llT += rf[w][1]; npT += rn[w]; }
        float N = fmaxf((float)npT, 1.0f);
        out[0] = llT / N;
        out[1] = lcT / N;
    }
}

// ---------------------------------------------------------------- launch
// ATTRIBUTION: k_select launched 3x (overwrite-idempotent).
// Y_new = (dur_us - ~63) / 3.
extern "C" void kernel_launch(void* const* d_in, const int* in_sizes, int n_in,
                              void* d_out, int out_size, void* d_ws, size_t ws_size,
                              hipStream_t stream)
{
    const float* loc_data  = (const float*)d_in[0];
    const float* conf_data = (const float*)d_in[1];
    const float* gt_boxes  = (const float*)d_in[2];
    const int*   gt_labels = (const int*)d_in[3];
    const float* priors    = (const float*)d_in[4];
    float* out = (float*)d_out;

    char* ws = (char*)d_ws;
    float* ll_b     = (float*)(ws + 0);
    int*   np_b     = (int*)(ws + 256);
    float* lc2      = (float*)(ws + 512);
    float* lc_part  = (float*)(ws + 1024);
    int*   conf_t   = (int*)(ws + 32768);
    float* mine     = (float*)(ws + 32768 + (size_t)BATCH * NPRIOR * 4);

    hipLaunchKernelGGL(k_match, dim3(BATCH), dim3(1024), 0, stream,
                       loc_data, gt_boxes, gt_labels, priors, conf_t, np_b, ll_b);
    hipLaunchKernelGGL(k_ce, dim3(CE_GRID), dim3(64), 0, stream,
                       conf_data, conf_t, mine, lc_part);
    hipLaunchKernelGGL(k_select, dim3(BATCH), dim3(1024), 0, stream,
                       mine, np_b, lc2);
    hipLaunchKernelGGL(k_select, dim3(BATCH), dim3(1024), 0, stream,
                       mine, np_b, lc2);
    hipLaunchKernelGGL(k_select, dim3(BATCH), dim3(1024), 0, stream,
                       mine, np_b, lc2);
    hipLaunchKernelGGL(k_final, dim3(1), dim3(1024), 0, stream,
                       lc_part, lc2, ll_b, np_b, out);
}

// Round 11
// 134.057 us; speedup vs baseline: 1.5068x; 1.3764x over previous
//
#include <hip/hip_runtime.h>
#include <math.h>

#define BATCH 64
#define NOBJ 16
#define NPRIOR 8732
#define NC 91
#define IMG 300.0f
#define GPB 1092                   // 8-row groups per batch (last group = 4 rows)
#define NGROUP (GPB * BATCH)       // 69888
#define CE_GRID 6144               // one-wave blocks

// ---------------------------------------------------------------- k_match
__global__ __launch_bounds__(1024) void k_match(
    const float* __restrict__ loc_data,
    const float* __restrict__ gt_boxes,
    const int*   __restrict__ gt_labels,
    const float* __restrict__ priors,
    int*   __restrict__ conf_t,
    int*   __restrict__ num_pos_b,
    float* __restrict__ ll_b)
{
    __shared__ float s_ov[NPRIOR];
    __shared__ unsigned char s_idx[NPRIOR];
    __shared__ float bx0[NOBJ], by0[NOBJ], bx1[NOBJ], by1[NOBJ], barea[NOBJ];
    __shared__ int   blab[NOBJ];
    __shared__ float rv[NOBJ][16];
    __shared__ int   ri[NOBJ][16];
    __shared__ int   bpi[NOBJ];
    __shared__ float red_f[16];
    __shared__ int   red_i[16];

    const int b    = blockIdx.x;
    const int tid  = threadIdx.x;
    const int lane = tid & 63;
    const int wave = tid >> 6;

    if (tid < NOBJ) {
        float4 g = ((const float4*)gt_boxes)[(size_t)b * NOBJ + tid];
        float x0 = g.x * (1.0f / IMG), y0 = g.y * (1.0f / IMG);
        float x1 = g.z * (1.0f / IMG), y1 = g.w * (1.0f / IMG);
        bx0[tid] = x0; by0[tid] = y0; bx1[tid] = x1; by1[tid] = y1;
        barea[tid] = (x1 - x0) * (y1 - y0);
        blab[tid] = gt_labels[b * NOBJ + tid];
    }
    __syncthreads();

    float bv[NOBJ];
    int   bi[NOBJ];
#pragma unroll
    for (int j = 0; j < NOBJ; j++) { bv[j] = -1.0f; bi[j] = 0x7fffffff; }

    for (int p = tid; p < NPRIOR; p += 1024) {
        float4 pr = ((const float4*)priors)[p];
        float cx = pr.x, cy = pr.y, w = pr.z, h = pr.w;
        float px0 = cx - 0.5f * w, py0 = cy - 0.5f * h;
        float px1 = cx + 0.5f * w, py1 = cy + 0.5f * h;
        float pa = w * h;
        float maxv = -1.0f; int maxj = 0;
#pragma unroll
        for (int j = 0; j < NOBJ; j++) {
            float ltx = fmaxf(bx0[j], px0), lty = fmaxf(by0[j], py0);
            float rbx = fminf(bx1[j], px1), rby = fminf(by1[j], py1);
            float iw = fmaxf(rbx - ltx, 0.0f), ih = fmaxf(rby - lty, 0.0f);
            float inter = iw * ih;
            float iou = inter / (barea[j] + pa - inter);
            if (iou > maxv) { maxv = iou; maxj = j; }
            if (iou > bv[j]) { bv[j] = iou; bi[j] = p; }
        }
        s_ov[p]  = maxv;
        s_idx[p] = (unsigned char)maxj;
    }

#pragma unroll
    for (int j = 0; j < NOBJ; j++) {
        float v = bv[j]; int ix = bi[j];
        for (int off = 32; off; off >>= 1) {
            float v2 = __shfl_xor(v, off);
            int   i2 = __shfl_xor(ix, off);
            if (v2 > v || (v2 == v && i2 < ix)) { v = v2; ix = i2; }
        }
        if (lane == 0) { rv[j][wave] = v; ri[j][wave] = ix; }
    }
    __syncthreads();
    if (tid < NOBJ) {
        int j = tid;
        float v = rv[j][0]; int ix = ri[j][0];
        for (int w2 = 1; w2 < 16; w2++) {
            float v2 = rv[j][w2]; int i2 = ri[j][w2];
            if (v2 > v || (v2 == v && i2 < ix)) { v = v2; ix = i2; }
        }
        bpi[j] = ix;
    }
    __syncthreads();
    if (tid == 0) {
        for (int j = 0; j < NOBJ; j++) s_ov[bpi[j]] = 2.0f;
        for (int j = 0; j < NOBJ; j++) s_idx[bpi[j]] = (unsigned char)j;
    }
    __syncthreads();

    int np_local = 0;
    float ll_local = 0.0f;
    for (int p = tid; p < NPRIOR; p += 1024) {
        float ov = s_ov[p];
        int ti = (int)s_idx[p];
        int conf = (ov < 0.5f) ? 0 : blab[ti];
        conf_t[(size_t)b * NPRIOR + p] = conf;
        if (conf > 0) {
            np_local++;
            float4 pr = ((const float4*)priors)[p];
            float cx = pr.x, cy = pr.y, w = pr.z, h = pr.w;
            float mx0 = bx0[ti], my0 = by0[ti], mx1 = bx1[ti], my1 = by1[ti];
            float g0 = ((mx0 + mx1) * 0.5f - cx) / (0.1f * w);
            float g1 = ((my0 + my1) * 0.5f - cy) / (0.1f * h);
            float g2 = logf((mx1 - mx0) / w) * 5.0f;
            float g3 = logf((my1 - my0) / h) * 5.0f;
            float4 lv = ((const float4*)loc_data)[(size_t)b * NPRIOR + p];
            float d0 = lv.x - g0, d1 = lv.y - g1, d2 = lv.z - g2, d3 = lv.w - g3;
            float a0 = fabsf(d0), a1 = fabsf(d1), a2 = fabsf(d2), a3 = fabsf(d3);
            ll_local += (a0 < 1.f ? 0.5f * d0 * d0 : a0 - 0.5f)
                      + (a1 < 1.f ? 0.5f * d1 * d1 : a1 - 0.5f)
                      + (a2 < 1.f ? 0.5f * d2 * d2 : a2 - 0.5f)
                      + (a3 < 1.f ? 0.5f * d3 * d3 : a3 - 0.5f);
        }
    }
    for (int off = 32; off; off >>= 1) {
        ll_local += __shfl_xor(ll_local, off);
        np_local += __shfl_xor(np_local, off);
    }
    if (lane == 0) { red_f[wave] = ll_local; red_i[wave] = np_local; }
    __syncthreads();
    if (tid == 0) {
        float ll = 0.0f; int np = 0;
        for (int w2 = 0; w2 < 16; w2++) { ll += red_f[w2]; np += red_i[w2]; }
        num_pos_b[b] = np;
        ll_b[b] = ll;
    }
}

// ---------------------------------------------------------------- k_ce
// One-wave persistent blocks, zero barriers, depth-2 register pipeline.

#define CE_ISSUE(gg, R0, R1, R2, NF)                                           \
    {   int b_ = (gg) / GPB, ci_ = (gg) - b_ * GPB;                            \
        int p0_ = ci_ * 8;                                                     \
        int rows_ = min(8, NPRIOR - p0_);                                      \
        NF = (rows_ * NC) >> 2;                                                \
        const float4* s_ = (const float4*)(conf_data + ((size_t)b_ * NPRIOR + p0_) * NC); \
        R0 = s_[tid];                                                          \
        if (tid + 64  < NF) R1 = s_[tid + 64];                                 \
        if (tid + 128 < NF) R2 = s_[tid + 128]; }

#define CT_LOAD(gg)                                                            \
    ( conf_t[(size_t)((gg) / GPB) * NPRIOR + ((gg) - ((gg) / GPB) * GPB) * 8 + (tid >> 3)] )

#define CE_WRITE(BUF, R0, R1, R2, NF)                                          \
    {   float4* d_ = (float4*)sbuf[BUF];                                       \
        d_[tid] = R0;                                                          \
        if (tid + 64  < NF) d_[tid + 64]  = R1;                                \
        if (tid + 128 < NF) d_[tid + 128] = R2; }

#define CE_COMPUTE(gg, BUF, TG)                                                \
    {   int b_ = (gg) / GPB, ci_ = (gg) - b_ * GPB;                            \
        int p0_ = ci_ * 8;                                                     \
        int rows_ = min(8, NPRIOR - p0_);                                      \
        int rr_ = tid >> 3, q_ = tid & 7;                                      \
        if (rr_ < rows_) {                                                     \
            const float* row_ = sbuf[BUF] + rr_ * NC;                          \
            float s_ = 0.0f;                                                   \
            _Pragma("unroll")                                                  \
            for (int i_ = q_; i_ < NC; i_ += 8) s_ += __expf(row_[i_]);        \
            s_ += __shfl_xor(s_, 1);                                           \
            s_ += __shfl_xor(s_, 2);                                           \
            s_ += __shfl_xor(s_, 4);                                           \
            if (q_ == 0) {                                                     \
                size_t o_ = (size_t)b_ * NPRIOR + p0_ + rr_;                   \
                int tgt_ = TG;                                                 \
                float ce_ = __logf(s_) - row_[tgt_];                           \
                if (tgt_ > 0) { pos_acc += ce_; mine[o_] = 0.0f; }             \
                else          { mine[o_] = fmaxf(ce_, 0.0f); }                 \
            } } }

__global__ __launch_bounds__(64) void k_ce(
    const float* __restrict__ conf_data,
    const int*   __restrict__ conf_t,
    float* __restrict__ mine,
    float* __restrict__ lc_part)
{
    __shared__ float sbuf[2][8 * NC];
    const int tid = threadIdx.x;
    const int G = CE_GRID;

    float4 a0, a1, a2, b0, b1, b2;
    int nfA = 0, nfB = 0;
    float pos_acc = 0.0f;

    int g = blockIdx.x;
    CE_ISSUE(g, a0, a1, a2, nfA);
    int tcur = CT_LOAD(g);
    if (g + G < NGROUP) CE_ISSUE(g + G, b0, b1, b2, nfB);
    CE_WRITE(0, a0, a1, a2, nfA);

    for (; g < NGROUP; g += 2 * G) {
        int tnext = (g + G < NGROUP) ? CT_LOAD(g + G) : 0;
        if (g + 2 * G < NGROUP) CE_ISSUE(g + 2 * G, a0, a1, a2, nfA);
        CE_COMPUTE(g, 0, tcur);
        if (g + G < NGROUP) {
            CE_WRITE(1, b0, b1, b2, nfB);
            int tn2 = (g + 2 * G < NGROUP) ? CT_LOAD(g + 2 * G) : 0;
            if (g + 3 * G < NGROUP) CE_ISSUE(g + 3 * G, b0, b1, b2, nfB);
            CE_COMPUTE(g + G, 1, tnext);
            if (g + 2 * G < NGROUP) CE_WRITE(0, a0, a1, a2, nfA);
            tcur = tn2;
        }
    }

    for (int off = 32; off; off >>= 1) pos_acc += __shfl_xor(pos_acc, off);
    if (tid == 0) lc_part[blockIdx.x] = pos_acc;
}

// ---------------------------------------------------------------- k_select
// Exact top-k value-sum WITHOUT histograms: values live in registers (9 per
// thread); the exact k-th largest key V_k is found by a 31-round MSB-greedy
// binary search (acc = max t with cnt_gt(t) >= k; V_k = acc+1). Each round
// is 9 register compares + wave shuffle-reduce + a 16-int LDS reduce — no
// LDS atomics (the DS pipe was the previous versions' wall), no ballots.
// Deterministic and exact; mine >= 0 so uint keys are order-isomorphic.
__global__ __launch_bounds__(1024) void k_select(
    const float* __restrict__ mine,
    const int*   __restrict__ num_pos_b,
    float* __restrict__ lc2)
{
    __shared__ int   s_cnt[16];
    __shared__ unsigned s_acc;
    __shared__ float red_f[16];
    __shared__ int   red_i[16];

    const int b = blockIdx.x;
    const int tid = threadIdx.x;
    const int lane = tid & 63;
    const int wave = tid >> 6;

    // coalesced load: thread tid holds elements tid, tid+1024, ..., tid+8192
    unsigned key[9];
#pragma unroll
    for (int j = 0; j < 9; j++) {
        int i = tid + j * 1024;
        key[j] = (i < NPRIOR) ? __float_as_uint(mine[(size_t)b * NPRIOR + i]) : 0u;
    }

    const int np = num_pos_b[b];
    const int kk = min(max(3 * np, 1), NPRIOR - 1);

    // MSB-greedy: after the loop, acc = max t with #{key > t} >= kk.
    // (bit 31 skipped: keys are non-negative-float patterns < 0x80000000)
    unsigned acc = 0u;
    for (int bit = 30; bit >= 0; bit--) {
        const unsigned tc = acc | (1u << bit);
        int c = 0;
#pragma unroll
        for (int j = 0; j < 9; j++) c += (key[j] > tc) ? 1 : 0;
        for (int off = 32; off; off >>= 1) c += __shfl_xor(c, off);
        if (lane == 0) s_cnt[wave] = c;
        __syncthreads();
        if (tid == 0) {
            int tot = 0;
#pragma unroll
            for (int w = 0; w < 16; w++) tot += s_cnt[w];
            s_acc = (tot >= kk) ? tc : acc;
        }
        __syncthreads();
        acc = s_acc;
        __syncthreads();            // s_acc stable before next round's write
    }

    const unsigned vk = acc + 1u;   // exact k-th largest key
    const float T = __uint_as_float(vk);

    float sum_gt = 0.0f;
    int   cnt_gt = 0;
#pragma unroll
    for (int j = 0; j < 9; j++) {
        if (key[j] > vk) { sum_gt += __uint_as_float(key[j]); cnt_gt++; }
    }
    for (int off = 32; off; off >>= 1) {
        sum_gt += __shfl_xor(sum_gt, off);
        cnt_gt += __shfl_xor(cnt_gt, off);
    }
    if (lane == 0) { red_f[wave] = sum_gt; red_i[wave] = cnt_gt; }
    __syncthreads();
    if (tid == 0) {
        float s = 0.0f; int c = 0;
#pragma unroll
        for (int w = 0; w < 16; w++) { s += red_f[w]; c += red_i[w]; }
        lc2[b] = s + (float)(kk - c) * T;
    }
}

// ---------------------------------------------------------------- k_final
__global__ __launch_bounds__(1024) void k_final(
    const float* __restrict__ lc_part, const float* __restrict__ lc2,
    const float* __restrict__ ll_b, const int* __restrict__ np_b,
    float* __restrict__ out)
{
    __shared__ float rf[16][2];
    __shared__ int   rn[16];
    const int tid = threadIdx.x;
    float lc = 0.0f;
    for (int i = tid; i < CE_GRID; i += 1024) lc += lc_part[i];
    float ll = 0.0f; int np = 0;
    if (tid < BATCH) { lc += lc2[tid]; ll = ll_b[tid]; np = np_b[tid]; }
    for (int off = 32; off; off >>= 1) {
        lc += __shfl_xor(lc, off);
        ll += __shfl_xor(ll, off);
        np += __shfl_xor(np, off);
    }
    const int lane = tid & 63, wave = tid >> 6;
    if (lane == 0) { rf[wave][0] = lc; rf[wave][1] = ll; rn[wave] = np; }
    __syncthreads();
    if (tid == 0) {
        float lcT = 0.0f, llT = 0.0f; int npT = 0;
        for (int w = 0; w < 16; w++) { lcT += rf[w][0]; llT += rf[w][1]; npT += rn[w]; }
        float N = fmaxf((float)npT, 1.0f);
        out[0] = llT / N;
        out[1] = lcT / N;
    }
}

// ---------------------------------------------------------------- launch
extern "C" void kernel_launch(void* const* d_in, const int* in_sizes, int n_in,
                              void* d_out, int out_size, void* d_ws, size_t ws_size,
                              hipStream_t stream)
{
    const float* loc_data  = (const float*)d_in[0];
    const float* conf_data = (const float*)d_in[1];
    const float* gt_boxes  = (const float*)d_in[2];
    const int*   gt_labels = (const int*)d_in[3];
    const float* priors    = (const float*)d_in[4];
    float* out = (float*)d_out;

    char* ws = (char*)d_ws;
    float* ll_b     = (float*)(ws + 0);
    int*   np_b     = (int*)(ws + 256);
    float* lc2      = (float*)(ws + 512);
    float* lc_part  = (float*)(ws + 1024);
    int*   conf_t   = (int*)(ws + 32768);
    float* mine     = (float*)(ws + 32768 + (size_t)BATCH * NPRIOR * 4);

    hipLaunchKernelGGL(k_match, dim3(BATCH), dim3(1024), 0, stream,
                       loc_data, gt_boxes, gt_labels, priors, conf_t, np_b, ll_b);
    hipLaunchKernelGGL(k_ce, dim3(CE_GRID), dim3(64), 0, stream,
                       conf_data, conf_t, mine, lc_part);
    hipLaunchKernelGGL(k_select, dim3(BATCH), dim3(1024), 0, stream,
                       mine, np_b, lc2);
    hipLaunchKernelGGL(k_final, dim3(1), dim3(1024), 0, stream,
                       lc_part, lc2, ll_b, np_b, out);
}

// Round 12
// 133.887 us; speedup vs baseline: 1.5087x; 1.0013x over previous
//
#include <hip/hip_runtime.h>
#include <math.h>

#define BATCH 64
#define NOBJ 16
#define NPRIOR 8732
#define NC 91
#define IMG 300.0f
#define GPB 1092                   // 8-row groups per batch (last group = 4 rows)
#define NGROUP (GPB * BATCH)       // 69888
#define CE_GRID 6144               // one-wave blocks
#define KPT 35                     // keys per thread in k_select (256*35 >= 8732)

// ---------------------------------------------------------------- k_match
__global__ __launch_bounds__(1024) void k_match(
    const float* __restrict__ loc_data,
    const float* __restrict__ gt_boxes,
    const int*   __restrict__ gt_labels,
    const float* __restrict__ priors,
    int*   __restrict__ conf_t,
    int*   __restrict__ num_pos_b,
    float* __restrict__ ll_b)
{
    __shared__ float s_ov[NPRIOR];
    __shared__ unsigned char s_idx[NPRIOR];
    __shared__ float bx0[NOBJ], by0[NOBJ], bx1[NOBJ], by1[NOBJ], barea[NOBJ];
    __shared__ int   blab[NOBJ];
    __shared__ float rv[NOBJ][16];
    __shared__ int   ri[NOBJ][16];
    __shared__ int   bpi[NOBJ];
    __shared__ float red_f[16];
    __shared__ int   red_i[16];

    const int b    = blockIdx.x;
    const int tid  = threadIdx.x;
    const int lane = tid & 63;
    const int wave = tid >> 6;

    if (tid < NOBJ) {
        float4 g = ((const float4*)gt_boxes)[(size_t)b * NOBJ + tid];
        float x0 = g.x * (1.0f / IMG), y0 = g.y * (1.0f / IMG);
        float x1 = g.z * (1.0f / IMG), y1 = g.w * (1.0f / IMG);
        bx0[tid] = x0; by0[tid] = y0; bx1[tid] = x1; by1[tid] = y1;
        barea[tid] = (x1 - x0) * (y1 - y0);
        blab[tid] = gt_labels[b * NOBJ + tid];
    }
    __syncthreads();

    float bv[NOBJ];
    int   bi[NOBJ];
#pragma unroll
    for (int j = 0; j < NOBJ; j++) { bv[j] = -1.0f; bi[j] = 0x7fffffff; }

    for (int p = tid; p < NPRIOR; p += 1024) {
        float4 pr = ((const float4*)priors)[p];
        float cx = pr.x, cy = pr.y, w = pr.z, h = pr.w;
        float px0 = cx - 0.5f * w, py0 = cy - 0.5f * h;
        float px1 = cx + 0.5f * w, py1 = cy + 0.5f * h;
        float pa = w * h;
        float maxv = -1.0f; int maxj = 0;
#pragma unroll
        for (int j = 0; j < NOBJ; j++) {
            float ltx = fmaxf(bx0[j], px0), lty = fmaxf(by0[j], py0);
            float rbx = fminf(bx1[j], px1), rby = fminf(by1[j], py1);
            float iw = fmaxf(rbx - ltx, 0.0f), ih = fmaxf(rby - lty, 0.0f);
            float inter = iw * ih;
            float iou = inter / (barea[j] + pa - inter);
            if (iou > maxv) { maxv = iou; maxj = j; }
            if (iou > bv[j]) { bv[j] = iou; bi[j] = p; }
        }
        s_ov[p]  = maxv;
        s_idx[p] = (unsigned char)maxj;
    }

#pragma unroll
    for (int j = 0; j < NOBJ; j++) {
        float v = bv[j]; int ix = bi[j];
        for (int off = 32; off; off >>= 1) {
            float v2 = __shfl_xor(v, off);
            int   i2 = __shfl_xor(ix, off);
            if (v2 > v || (v2 == v && i2 < ix)) { v = v2; ix = i2; }
        }
        if (lane == 0) { rv[j][wave] = v; ri[j][wave] = ix; }
    }
    __syncthreads();
    if (tid < NOBJ) {
        int j = tid;
        float v = rv[j][0]; int ix = ri[j][0];
        for (int w2 = 1; w2 < 16; w2++) {
            float v2 = rv[j][w2]; int i2 = ri[j][w2];
            if (v2 > v || (v2 == v && i2 < ix)) { v = v2; ix = i2; }
        }
        bpi[j] = ix;
    }
    __syncthreads();
    if (tid == 0) {
        for (int j = 0; j < NOBJ; j++) s_ov[bpi[j]] = 2.0f;
        for (int j = 0; j < NOBJ; j++) s_idx[bpi[j]] = (unsigned char)j;
    }
    __syncthreads();

    int np_local = 0;
    float ll_local = 0.0f;
    for (int p = tid; p < NPRIOR; p += 1024) {
        float ov = s_ov[p];
        int ti = (int)s_idx[p];
        int conf = (ov < 0.5f) ? 0 : blab[ti];
        conf_t[(size_t)b * NPRIOR + p] = conf;
        if (conf > 0) {
            np_local++;
            float4 pr = ((const float4*)priors)[p];
            float cx = pr.x, cy = pr.y, w = pr.z, h = pr.w;
            float mx0 = bx0[ti], my0 = by0[ti], mx1 = bx1[ti], my1 = by1[ti];
            float g0 = ((mx0 + mx1) * 0.5f - cx) / (0.1f * w);
            float g1 = ((my0 + my1) * 0.5f - cy) / (0.1f * h);
            float g2 = logf((mx1 - mx0) / w) * 5.0f;
            float g3 = logf((my1 - my0) / h) * 5.0f;
            float4 lv = ((const float4*)loc_data)[(size_t)b * NPRIOR + p];
            float d0 = lv.x - g0, d1 = lv.y - g1, d2 = lv.z - g2, d3 = lv.w - g3;
            float a0 = fabsf(d0), a1 = fabsf(d1), a2 = fabsf(d2), a3 = fabsf(d3);
            ll_local += (a0 < 1.f ? 0.5f * d0 * d0 : a0 - 0.5f)
                      + (a1 < 1.f ? 0.5f * d1 * d1 : a1 - 0.5f)
                      + (a2 < 1.f ? 0.5f * d2 * d2 : a2 - 0.5f)
                      + (a3 < 1.f ? 0.5f * d3 * d3 : a3 - 0.5f);
        }
    }
    for (int off = 32; off; off >>= 1) {
        ll_local += __shfl_xor(ll_local, off);
        np_local += __shfl_xor(np_local, off);
    }
    if (lane == 0) { red_f[wave] = ll_local; red_i[wave] = np_local; }
    __syncthreads();
    if (tid == 0) {
        float ll = 0.0f; int np = 0;
        for (int w2 = 0; w2 < 16; w2++) { ll += red_f[w2]; np += red_i[w2]; }
        num_pos_b[b] = np;
        ll_b[b] = ll;
    }
}

// ---------------------------------------------------------------- k_ce
// One-wave persistent blocks, zero barriers, depth-2 register pipeline.

#define CE_ISSUE(gg, R0, R1, R2, NF)                                           \
    {   int b_ = (gg) / GPB, ci_ = (gg) - b_ * GPB;                            \
        int p0_ = ci_ * 8;                                                     \
        int rows_ = min(8, NPRIOR - p0_);                                      \
        NF = (rows_ * NC) >> 2;                                                \
        const float4* s_ = (const float4*)(conf_data + ((size_t)b_ * NPRIOR + p0_) * NC); \
        R0 = s_[tid];                                                          \
        if (tid + 64  < NF) R1 = s_[tid + 64];                                 \
        if (tid + 128 < NF) R2 = s_[tid + 128]; }

#define CT_LOAD(gg)                                                            \
    ( conf_t[(size_t)((gg) / GPB) * NPRIOR + ((gg) - ((gg) / GPB) * GPB) * 8 + (tid >> 3)] )

#define CE_WRITE(BUF, R0, R1, R2, NF)                                          \
    {   float4* d_ = (float4*)sbuf[BUF];                                       \
        d_[tid] = R0;                                                          \
        if (tid + 64  < NF) d_[tid + 64]  = R1;                                \
        if (tid + 128 < NF) d_[tid + 128] = R2; }

#define CE_COMPUTE(gg, BUF, TG)                                                \
    {   int b_ = (gg) / GPB, ci_ = (gg) - b_ * GPB;                            \
        int p0_ = ci_ * 8;                                                     \
        int rows_ = min(8, NPRIOR - p0_);                                      \
        int rr_ = tid >> 3, q_ = tid & 7;                                      \
        if (rr_ < rows_) {                                                     \
            const float* row_ = sbuf[BUF] + rr_ * NC;                          \
            float s_ = 0.0f;                                                   \
            _Pragma("unroll")                                                  \
            for (int i_ = q_; i_ < NC; i_ += 8) s_ += __expf(row_[i_]);        \
            s_ += __shfl_xor(s_, 1);                                           \
            s_ += __shfl_xor(s_, 2);                                           \
            s_ += __shfl_xor(s_, 4);                                           \
            if (q_ == 0) {                                                     \
                size_t o_ = (size_t)b_ * NPRIOR + p0_ + rr_;                   \
                int tgt_ = TG;                                                 \
                float ce_ = __logf(s_) - row_[tgt_];                           \
                if (tgt_ > 0) { pos_acc += ce_; mine[o_] = 0.0f; }             \
                else          { mine[o_] = fmaxf(ce_, 0.0f); }                 \
            } } }

__global__ __launch_bounds__(64) void k_ce(
    const float* __restrict__ conf_data,
    const int*   __restrict__ conf_t,
    float* __restrict__ mine,
    float* __restrict__ lc_part)
{
    __shared__ float sbuf[2][8 * NC];
    const int tid = threadIdx.x;
    const int G = CE_GRID;

    float4 a0, a1, a2, b0, b1, b2;
    int nfA = 0, nfB = 0;
    float pos_acc = 0.0f;

    int g = blockIdx.x;
    CE_ISSUE(g, a0, a1, a2, nfA);
    int tcur = CT_LOAD(g);
    if (g + G < NGROUP) CE_ISSUE(g + G, b0, b1, b2, nfB);
    CE_WRITE(0, a0, a1, a2, nfA);

    for (; g < NGROUP; g += 2 * G) {
        int tnext = (g + G < NGROUP) ? CT_LOAD(g + G) : 0;
        if (g + 2 * G < NGROUP) CE_ISSUE(g + 2 * G, a0, a1, a2, nfA);
        CE_COMPUTE(g, 0, tcur);
        if (g + G < NGROUP) {
            CE_WRITE(1, b0, b1, b2, nfB);
            int tn2 = (g + 2 * G < NGROUP) ? CT_LOAD(g + 2 * G) : 0;
            if (g + 3 * G < NGROUP) CE_ISSUE(g + 3 * G, b0, b1, b2, nfB);
            CE_COMPUTE(g + G, 1, tnext);
            if (g + 2 * G < NGROUP) CE_WRITE(0, a0, a1, a2, nfA);
            tcur = tn2;
        }
    }

    for (int off = 32; off; off >>= 1) pos_acc += __shfl_xor(pos_acc, off);
    if (tid == 0) lc_part[blockIdx.x] = pos_acc;
}

// ---------------------------------------------------------------- k_select
// Exact top-k value-sum via 31-round MSB-greedy binary search on register-
// resident keys. 256 threads (4 waves) — the 16-wave version's barrier
// rounds cost ~5.6k cyc each; 4-wave blocks + ONE barrier per round
// (double-buffered s_cnt, redundant uniform tot on every thread) cut the
// per-round overhead ~10x. No LDS atomics, no serial thread-0 section.
__global__ __launch_bounds__(256) void k_select(
    const float* __restrict__ mine,
    const int*   __restrict__ num_pos_b,
    float* __restrict__ lc2)
{
    __shared__ int   s_cnt[2][4];
    __shared__ float red_f[4];
    __shared__ int   red_i[4];

    const int b = blockIdx.x;
    const int tid = threadIdx.x;
    const int lane = tid & 63;
    const int wave = tid >> 6;

    // coalesced: thread t holds elements t, t+256, ..., t+34*256
    unsigned key[KPT];
#pragma unroll
    for (int j = 0; j < KPT; j++) {
        int i = tid + j * 256;
        key[j] = (i < NPRIOR) ? __float_as_uint(mine[(size_t)b * NPRIOR + i]) : 0u;
    }

    const int np = num_pos_b[b];
    const int kk = min(max(3 * np, 1), NPRIOR - 1);

    // MSB-greedy: after the loop, acc = max t with #{key > t} >= kk,
    // so V_k (exact k-th largest key) = acc + 1. Bit 31 skipped (keys are
    // non-negative float patterns). Padding zeros never counted (tc >= 1).
    unsigned acc = 0u;
    for (int bit = 30; bit >= 0; bit--) {
        const unsigned tc = acc | (1u << bit);
        int c = 0;
#pragma unroll
        for (int j = 0; j < KPT; j++) c += (key[j] > tc) ? 1 : 0;
        for (int off = 32; off; off >>= 1) c += __shfl_xor(c, off);
        if (lane == 0) s_cnt[bit & 1][wave] = c;
        __syncthreads();                         // ONE barrier per round
        int tot = s_cnt[bit & 1][0] + s_cnt[bit & 1][1]
                + s_cnt[bit & 1][2] + s_cnt[bit & 1][3];
        if (tot >= kk) acc = tc;                 // uniform across block
        // next round writes the OTHER buffer -> no write-after-read hazard
    }

    const unsigned vk = acc + 1u;
    const float T = __uint_as_float(vk);

    float sum_gt = 0.0f;
    int   cnt_gt = 0;
#pragma unroll
    for (int j = 0; j < KPT; j++) {
        if (key[j] > vk) { sum_gt += __uint_as_float(key[j]); cnt_gt++; }
    }
    for (int off = 32; off; off >>= 1) {
        sum_gt += __shfl_xor(sum_gt, off);
        cnt_gt += __shfl_xor(cnt_gt, off);
    }
    if (lane == 0) { red_f[wave] = sum_gt; red_i[wave] = cnt_gt; }
    __syncthreads();
    if (tid == 0) {
        float s = red_f[0] + red_f[1] + red_f[2] + red_f[3];
        int   c = red_i[0] + red_i[1] + red_i[2] + red_i[3];
        lc2[b] = s + (float)(kk - c) * T;
    }
}

// ---------------------------------------------------------------- k_final
__global__ __launch_bounds__(1024) void k_final(
    const float* __restrict__ lc_part, const float* __restrict__ lc2,
    const float* __restrict__ ll_b, const int* __restrict__ np_b,
    float* __restrict__ out)
{
    __shared__ float rf[16][2];
    __shared__ int   rn[16];
    const int tid = threadIdx.x;
    float lc = 0.0f;
    for (int i = tid; i < CE_GRID; i += 1024) lc += lc_part[i];
    float ll = 0.0f; int np = 0;
    if (tid < BATCH) { lc += lc2[tid]; ll = ll_b[tid]; np = np_b[tid]; }
    for (int off = 32; off; off >>= 1) {
        lc += __shfl_xor(lc, off);
        ll += __shfl_xor(ll, off);
        np += __shfl_xor(np, off);
    }
    const int lane = tid & 63, wave = tid >> 6;
    if (lane == 0) { rf[wave][0] = lc; rf[wave][1] = ll; rn[wave] = np; }
    __syncthreads();
    if (tid == 0) {
        float lcT = 0.0f, llT = 0.0f; int npT = 0;
        for (int w = 0; w < 16; w++) { lcT += rf[w][0]; llT += rf[w][1]; npT += rn[w]; }
        float N = fmaxf((float)npT, 1.0f);
        out[0] = llT / N;
        out[1] = lcT / N;
    }
}

// ---------------------------------------------------------------- launch
extern "C" void kernel_launch(void* const* d_in, const int* in_sizes, int n_in,
                              void* d_out, int out_size, void* d_ws, size_t ws_size,
                              hipStream_t stream)
{
    const float* loc_data  = (const float*)d_in[0];
    const float* conf_data = (const float*)d_in[1];
    const float* gt_boxes  = (const float*)d_in[2];
    const int*   gt_labels = (const int*)d_in[3];
    const float* priors    = (const float*)d_in[4];
    float* out = (float*)d_out;

    char* ws = (char*)d_ws;
    float* ll_b     = (float*)(ws + 0);
    int*   np_b     = (int*)(ws + 256);
    float* lc2      = (float*)(ws + 512);
    float* lc_part  = (float*)(ws + 1024);
    int*   conf_t   = (int*)(ws + 32768);
    float* mine     = (float*)(ws + 32768 + (size_t)BATCH * NPRIOR * 4);

    hipLaunchKernelGGL(k_match, dim3(BATCH), dim3(1024), 0, stream,
                       loc_data, gt_boxes, gt_labels, priors, conf_t, np_b, ll_b);
    hipLaunchKernelGGL(k_ce, dim3(CE_GRID), dim3(64), 0, stream,
                       conf_data, conf_t, mine, lc_part);
    hipLaunchKernelGGL(k_select, dim3(BATCH), dim3(256), 0, stream,
                       mine, np_b, lc2);
    hipLaunchKernelGGL(k_final, dim3(1), dim3(1024), 0, stream,
                       lc_part, lc2, ll_b, np_b, out);
}

// Round 13
// 118.872 us; speedup vs baseline: 1.6993x; 1.1263x over previous
//
#include <hip/hip_runtime.h>
#include <math.h>

#define BATCH 64
#define NOBJ 16
#define NPRIOR 8732
#define NC 91
#define IMG 300.0f
#define GPB 1092                   // 8-row groups per batch (last group = 4 rows)
#define NGROUP (GPB * BATCH)       // 69888
#define CE_GRID 6144               // one-wave blocks
#define BINS 2048                  // fixed-point bins: bin = min(2047, v*64)
#define BCAP 1024                  // boundary-bin capacity (~80 expected)

// ---------------------------------------------------------------- k_match
__global__ __launch_bounds__(1024) void k_match(
    const float* __restrict__ loc_data,
    const float* __restrict__ gt_boxes,
    const int*   __restrict__ gt_labels,
    const float* __restrict__ priors,
    int*   __restrict__ conf_t,
    int*   __restrict__ num_pos_b,
    float* __restrict__ ll_b)
{
    __shared__ float s_ov[NPRIOR];
    __shared__ unsigned char s_idx[NPRIOR];
    __shared__ float bx0[NOBJ], by0[NOBJ], bx1[NOBJ], by1[NOBJ], barea[NOBJ];
    __shared__ int   blab[NOBJ];
    __shared__ float rv[NOBJ][16];
    __shared__ int   ri[NOBJ][16];
    __shared__ int   bpi[NOBJ];
    __shared__ float red_f[16];
    __shared__ int   red_i[16];

    const int b    = blockIdx.x;
    const int tid  = threadIdx.x;
    const int lane = tid & 63;
    const int wave = tid >> 6;

    if (tid < NOBJ) {
        float4 g = ((const float4*)gt_boxes)[(size_t)b * NOBJ + tid];
        float x0 = g.x * (1.0f / IMG), y0 = g.y * (1.0f / IMG);
        float x1 = g.z * (1.0f / IMG), y1 = g.w * (1.0f / IMG);
        bx0[tid] = x0; by0[tid] = y0; bx1[tid] = x1; by1[tid] = y1;
        barea[tid] = (x1 - x0) * (y1 - y0);
        blab[tid] = gt_labels[b * NOBJ + tid];
    }
    __syncthreads();

    float bv[NOBJ];
    int   bi[NOBJ];
#pragma unroll
    for (int j = 0; j < NOBJ; j++) { bv[j] = -1.0f; bi[j] = 0x7fffffff; }

    for (int p = tid; p < NPRIOR; p += 1024) {
        float4 pr = ((const float4*)priors)[p];
        float cx = pr.x, cy = pr.y, w = pr.z, h = pr.w;
        float px0 = cx - 0.5f * w, py0 = cy - 0.5f * h;
        float px1 = cx + 0.5f * w, py1 = cy + 0.5f * h;
        float pa = w * h;
        float maxv = -1.0f; int maxj = 0;
#pragma unroll
        for (int j = 0; j < NOBJ; j++) {
            float ltx = fmaxf(bx0[j], px0), lty = fmaxf(by0[j], py0);
            float rbx = fminf(bx1[j], px1), rby = fminf(by1[j], py1);
            float iw = fmaxf(rbx - ltx, 0.0f), ih = fmaxf(rby - lty, 0.0f);
            float inter = iw * ih;
            float iou = inter / (barea[j] + pa - inter);
            if (iou > maxv) { maxv = iou; maxj = j; }
            if (iou > bv[j]) { bv[j] = iou; bi[j] = p; }
        }
        s_ov[p]  = maxv;
        s_idx[p] = (unsigned char)maxj;
    }

#pragma unroll
    for (int j = 0; j < NOBJ; j++) {
        float v = bv[j]; int ix = bi[j];
        for (int off = 32; off; off >>= 1) {
            float v2 = __shfl_xor(v, off);
            int   i2 = __shfl_xor(ix, off);
            if (v2 > v || (v2 == v && i2 < ix)) { v = v2; ix = i2; }
        }
        if (lane == 0) { rv[j][wave] = v; ri[j][wave] = ix; }
    }
    __syncthreads();
    if (tid < NOBJ) {
        int j = tid;
        float v = rv[j][0]; int ix = ri[j][0];
        for (int w2 = 1; w2 < 16; w2++) {
            float v2 = rv[j][w2]; int i2 = ri[j][w2];
            if (v2 > v || (v2 == v && i2 < ix)) { v = v2; ix = i2; }
        }
        bpi[j] = ix;
    }
    __syncthreads();
    if (tid == 0) {
        for (int j = 0; j < NOBJ; j++) s_ov[bpi[j]] = 2.0f;
        for (int j = 0; j < NOBJ; j++) s_idx[bpi[j]] = (unsigned char)j;
    }
    __syncthreads();

    int np_local = 0;
    float ll_local = 0.0f;
    for (int p = tid; p < NPRIOR; p += 1024) {
        float ov = s_ov[p];
        int ti = (int)s_idx[p];
        int conf = (ov < 0.5f) ? 0 : blab[ti];
        conf_t[(size_t)b * NPRIOR + p] = conf;
        if (conf > 0) {
            np_local++;
            float4 pr = ((const float4*)priors)[p];
            float cx = pr.x, cy = pr.y, w = pr.z, h = pr.w;
            float mx0 = bx0[ti], my0 = by0[ti], mx1 = bx1[ti], my1 = by1[ti];
            float g0 = ((mx0 + mx1) * 0.5f - cx) / (0.1f * w);
            float g1 = ((my0 + my1) * 0.5f - cy) / (0.1f * h);
            float g2 = logf((mx1 - mx0) / w) * 5.0f;
            float g3 = logf((my1 - my0) / h) * 5.0f;
            float4 lv = ((const float4*)loc_data)[(size_t)b * NPRIOR + p];
            float d0 = lv.x - g0, d1 = lv.y - g1, d2 = lv.z - g2, d3 = lv.w - g3;
            float a0 = fabsf(d0), a1 = fabsf(d1), a2 = fabsf(d2), a3 = fabsf(d3);
            ll_local += (a0 < 1.f ? 0.5f * d0 * d0 : a0 - 0.5f)
                      + (a1 < 1.f ? 0.5f * d1 * d1 : a1 - 0.5f)
                      + (a2 < 1.f ? 0.5f * d2 * d2 : a2 - 0.5f)
                      + (a3 < 1.f ? 0.5f * d3 * d3 : a3 - 0.5f);
        }
    }
    for (int off = 32; off; off >>= 1) {
        ll_local += __shfl_xor(ll_local, off);
        np_local += __shfl_xor(np_local, off);
    }
    if (lane == 0) { red_f[wave] = ll_local; red_i[wave] = np_local; }
    __syncthreads();
    if (tid == 0) {
        float ll = 0.0f; int np = 0;
        for (int w2 = 0; w2 < 16; w2++) { ll += red_f[w2]; np += red_i[w2]; }
        num_pos_b[b] = np;
        ll_b[b] = ll;
    }
}

// ---------------------------------------------------------------- k_ce
// One-wave persistent blocks, zero barriers, depth-2 register pipeline.

#define CE_ISSUE(gg, R0, R1, R2, NF)                                           \
    {   int b_ = (gg) / GPB, ci_ = (gg) - b_ * GPB;                            \
        int p0_ = ci_ * 8;                                                     \
        int rows_ = min(8, NPRIOR - p0_);                                      \
        NF = (rows_ * NC) >> 2;                                                \
        const float4* s_ = (const float4*)(conf_data + ((size_t)b_ * NPRIOR + p0_) * NC); \
        R0 = s_[tid];                                                          \
        if (tid + 64  < NF) R1 = s_[tid + 64];                                 \
        if (tid + 128 < NF) R2 = s_[tid + 128]; }

#define CT_LOAD(gg)                                                            \
    ( conf_t[(size_t)((gg) / GPB) * NPRIOR + ((gg) - ((gg) / GPB) * GPB) * 8 + (tid >> 3)] )

#define CE_WRITE(BUF, R0, R1, R2, NF)                                          \
    {   float4* d_ = (float4*)sbuf[BUF];                                       \
        d_[tid] = R0;                                                          \
        if (tid + 64  < NF) d_[tid + 64]  = R1;                                \
        if (tid + 128 < NF) d_[tid + 128] = R2; }

#define CE_COMPUTE(gg, BUF, TG)                                                \
    {   int b_ = (gg) / GPB, ci_ = (gg) - b_ * GPB;                            \
        int p0_ = ci_ * 8;                                                     \
        int rows_ = min(8, NPRIOR - p0_);                                      \
        int rr_ = tid >> 3, q_ = tid & 7;                                      \
        if (rr_ < rows_) {                                                     \
            const float* row_ = sbuf[BUF] + rr_ * NC;                          \
            float s_ = 0.0f;                                                   \
            _Pragma("unroll")                                                  \
            for (int i_ = q_; i_ < NC; i_ += 8) s_ += __expf(row_[i_]);        \
            s_ += __shfl_xor(s_, 1);                                           \
            s_ += __shfl_xor(s_, 2);                                           \
            s_ += __shfl_xor(s_, 4);                                           \
            if (q_ == 0) {                                                     \
                size_t o_ = (size_t)b_ * NPRIOR + p0_ + rr_;                   \
                int tgt_ = TG;                                                 \
                float ce_ = __logf(s_) - row_[tgt_];                           \
                if (tgt_ > 0) { pos_acc += ce_; mine[o_] = 0.0f; }             \
                else          { mine[o_] = fmaxf(ce_, 0.0f); }                 \
            } } }

__global__ __launch_bounds__(64) void k_ce(
    const float* __restrict__ conf_data,
    const int*   __restrict__ conf_t,
    float* __restrict__ mine,
    float* __restrict__ lc_part)
{
    __shared__ float sbuf[2][8 * NC];
    const int tid = threadIdx.x;
    const int G = CE_GRID;

    float4 a0, a1, a2, b0, b1, b2;
    int nfA = 0, nfB = 0;
    float pos_acc = 0.0f;

    int g = blockIdx.x;
    CE_ISSUE(g, a0, a1, a2, nfA);
    int tcur = CT_LOAD(g);
    if (g + G < NGROUP) CE_ISSUE(g + G, b0, b1, b2, nfB);
    CE_WRITE(0, a0, a1, a2, nfA);

    for (; g < NGROUP; g += 2 * G) {
        int tnext = (g + G < NGROUP) ? CT_LOAD(g + G) : 0;
        if (g + 2 * G < NGROUP) CE_ISSUE(g + 2 * G, a0, a1, a2, nfA);
        CE_COMPUTE(g, 0, tcur);
        if (g + G < NGROUP) {
            CE_WRITE(1, b0, b1, b2, nfB);
            int tn2 = (g + 2 * G < NGROUP) ? CT_LOAD(g + 2 * G) : 0;
            if (g + 3 * G < NGROUP) CE_ISSUE(g + 3 * G, b0, b1, b2, nfB);
            CE_COMPUTE(g + G, 1, tnext);
            if (g + 2 * G < NGROUP) CE_WRITE(0, a0, a1, a2, nfA);
            tcur = tn2;
        }
    }

    for (int off = 32; off; off >>= 1) pos_acc += __shfl_xor(pos_acc, off);
    if (tid == 0) lc_part[blockIdx.x] = pos_acc;
}

// ---------------------------------------------------------------- k_select
// One-pass fixed-point radix select (~7 barrier rounds — the empirical cost
// law on this chip is ~2.6k cyc per barrier round at 1 block/CU, so round
// count, not instruction count, dominates). Values are bounded (< 32), so
// bin = min(2047, int(v*64)) is monotone. One LDS histogram pass (spread
// atomics, no same-address pathology), one pair-per-thread suffix scan to
// find the boundary bin, then exact k-th value T via all-pairs rank on the
// ~30-80 boundary-bin values. sum_topk = sum_{v>T} v + (kk - cnt_gt)*T.
__global__ __launch_bounds__(1024) void k_select(
    const float* __restrict__ mine,
    const int*   __restrict__ num_pos_b,
    float* __restrict__ lc2)
{
    __shared__ int   hist[BINS];        // 8 KB
    __shared__ int   wtot[16];
    __shared__ float bvals[BCAP];       // 4 KB
    __shared__ int   s_bcnt;
    __shared__ int   s_B0, s_r;
    __shared__ float s_T;
    __shared__ float red_f[16];
    __shared__ int   red_i[16];

    const int b = blockIdx.x;
    const int tid = threadIdx.x;
    const int lane = tid & 63;
    const int wave = tid >> 6;

    // registers: 9 values + bins per thread (coalesced load)
    float v[9];
    int   bin[9];
#pragma unroll
    for (int j = 0; j < 9; j++) {
        int i = tid + j * 1024;
        float x = (i < NPRIOR) ? mine[(size_t)b * NPRIOR + i] : 0.0f;
        v[j] = x;
        bin[j] = (i < NPRIOR) ? min((int)(x * 64.0f), BINS - 1) : -1;
    }

    hist[tid] = 0;
    hist[tid + 1024] = 0;
    if (tid == 0) s_bcnt = 0;
    __syncthreads();

#pragma unroll
    for (int j = 0; j < 9; j++)
        if (bin[j] >= 0) atomicAdd(&hist[bin[j]], 1);

    const int np = num_pos_b[b];
    const int kk = min(max(3 * np, 1), NPRIOR - 1);
    __syncthreads();

    // suffix scan over bin-pairs: thread t owns bins (2t, 2t+1)
    const int h0 = hist[2 * tid], h1 = hist[2 * tid + 1];
    const int ps = h0 + h1;
    int incl = ps;                       // inclusive suffix sum within wave
#pragma unroll
    for (int off = 1; off < 64; off <<= 1) {
        int t = __shfl_down(incl, off);
        incl += (lane + off < 64) ? t : 0;
    }
    if (lane == 0) wtot[wave] = incl;
    __syncthreads();
    int hi = 0;
#pragma unroll
    for (int w = 0; w < 16; w++) if (w > wave) hi += wtot[w];
    const int suf = (incl - ps) + hi;    // count in pairs strictly above
    // boundary bin: cnt_gt(bin) < kk <= cnt_gt(bin) + hist[bin]
    if (suf < kk && kk <= suf + h1)            { s_B0 = 2 * tid + 1; s_r = kk - suf; }
    const int suf1 = suf + h1;
    if (suf1 < kk && kk <= suf1 + h0)          { s_B0 = 2 * tid;     s_r = kk - suf1; }
    __syncthreads();

    const int B0 = s_B0;
    const int r  = s_r;

    // partial sums above boundary; collect boundary-bin values
    float sgt = 0.0f; int cgt = 0;
#pragma unroll
    for (int j = 0; j < 9; j++) {
        if (bin[j] > B0)       { sgt += v[j]; cgt++; }
        else if (bin[j] == B0) {
            int ix = atomicAdd(&s_bcnt, 1);
            if (ix < BCAP) bvals[ix] = v[j];
        }
    }
    __syncthreads();
    const int m = min(s_bcnt, BCAP);

    // exact k-th value T inside boundary bin via all-pairs rank
    for (int i = tid; i < m; i += 1024) {
        float vi = bvals[i];
        int c = 0, e = 0;
        for (int j2 = 0; j2 < m; j2++) {
            float vj = bvals[j2];
            c += (vj > vi) ? 1 : 0;
            e += (vj == vi) ? 1 : 0;
        }
        if (c < r && r <= c + e) s_T = vi;   // unique value; equal writers benign
    }
    __syncthreads();
    const float T = s_T;

    for (int i = tid; i < m; i += 1024)
        if (bvals[i] > T) { sgt += bvals[i]; cgt++; }

    for (int off = 32; off; off >>= 1) {
        sgt += __shfl_xor(sgt, off);
        cgt += __shfl_xor(cgt, off);
    }
    if (lane == 0) { red_f[wave] = sgt; red_i[wave] = cgt; }
    __syncthreads();
    if (tid == 0) {
        float s = 0.0f; int c = 0;
#pragma unroll
        for (int w = 0; w < 16; w++) { s += red_f[w]; c += red_i[w]; }
        lc2[b] = s + (float)(kk - c) * T;
    }
}

// ---------------------------------------------------------------- k_final
__global__ __launch_bounds__(1024) void k_final(
    const float* __restrict__ lc_part, const float* __restrict__ lc2,
    const float* __restrict__ ll_b, const int* __restrict__ np_b,
    float* __restrict__ out)
{
    __shared__ float rf[16][2];
    __shared__ int   rn[16];
    const int tid = threadIdx.x;
    float lc = 0.0f;
    for (int i = tid; i < CE_GRID; i += 1024) lc += lc_part[i];
    float ll = 0.0f; int np = 0;
    if (tid < BATCH) { lc += lc2[tid]; ll = ll_b[tid]; np = np_b[tid]; }
    for (int off = 32; off; off >>= 1) {
        lc += __shfl_xor(lc, off);
        ll += __shfl_xor(ll, off);
        np += __shfl_xor(np, off);
    }
    const int lane = tid & 63, wave = tid >> 6;
    if (lane == 0) { rf[wave][0] = lc; rf[wave][1] = ll; rn[wave] = np; }
    __syncthreads();
    if (tid == 0) {
        float lcT = 0.0f, llT = 0.0f; int npT = 0;
        for (int w = 0; w < 16; w++) { lcT += rf[w][0]; llT += rf[w][1]; npT += rn[w]; }
        float N = fmaxf((float)npT, 1.0f);
        out[0] = llT / N;
        out[1] = lcT / N;
    }
}

// ---------------------------------------------------------------- launch
extern "C" void kernel_launch(void* const* d_in, const int* in_sizes, int n_in,
                              void* d_out, int out_size, void* d_ws, size_t ws_size,
                              hipStream_t stream)
{
    const float* loc_data  = (const float*)d_in[0];
    const float* conf_data = (const float*)d_in[1];
    const float* gt_boxes  = (const float*)d_in[2];
    const int*   gt_labels = (const int*)d_in[3];
    const float* priors    = (const float*)d_in[4];
    float* out = (float*)d_out;

    char* ws = (char*)d_ws;
    float* ll_b     = (float*)(ws + 0);
    int*   np_b     = (int*)(ws + 256);
    float* lc2      = (float*)(ws + 512);
    float* lc_part  = (float*)(ws + 1024);
    int*   conf_t   = (int*)(ws + 32768);
    float* mine     = (float*)(ws + 32768 + (size_t)BATCH * NPRIOR * 4);

    hipLaunchKernelGGL(k_match, dim3(BATCH), dim3(1024), 0, stream,
                       loc_data, gt_boxes, gt_labels, priors, conf_t, np_b, ll_b);
    hipLaunchKernelGGL(k_ce, dim3(CE_GRID), dim3(64), 0, stream,
                       conf_data, conf_t, mine, lc_part);
    hipLaunchKernelGGL(k_select, dim3(BATCH), dim3(1024), 0, stream,
                       mine, np_b, lc2);
    hipLaunchKernelGGL(k_final, dim3(1), dim3(1024), 0, stream,
                       lc_part, lc2, ll_b, np_b, out);
}